// Round 10
// baseline (2404.446 us; speedup 1.0000x reference)
//
#include <hip/hip_runtime.h>
#include <hip/hip_bf16.h>

// ============================================================================
// GRU seq2seq (3-layer enc + 3-cell dec + linear), B=2048, H=60, F=1, fp32.
//
// Round 10 = round 9 (f16 ring, 681us/phase) + 2 independent batch
// sub-problems per block:
//  - 64 blocks x 32 rows; each block runs TWO 16-row pipelines (sub0/sub1)
//    in one instruction stream per slot (unrolled, compile-time indexed).
//    Two independent read->MFMA->act->write chains interleave, filling the
//    ~1000cy/slot of exposed latency that r9's lockstep left idle; barrier
//    and drain costs amortize over 2x work. Weights shared between subs.
//  - y-duty: sub0 on g0w0, sub1 on g0w1; lin_w hi-only (err ~2e-4).
//  - Kept: f16 single-plane ring (stride 72), mmh h-path (W hi+lo) /
//    mmx x-path (hi), fp32 h in regs, x prefetch, lgkmcnt-only barrier,
//    launch_bounds(768,3).
// ============================================================================

typedef float    f32x4 __attribute__((ext_vector_type(4)));
typedef _Float16 f16x8 __attribute__((ext_vector_type(8)));

#define RSTR 72               // ring row stride in shorts
#define REG  (16 * RSTR)      // shorts per region
#define SUBSZ (6 * REG)       // shorts per sub-problem ring

struct CellB  { const float* bih; const float* bhh; const float* wih_vec; };
struct PhaseArgs {
  const float* xseq;          // [2048][512] fp32
  const unsigned short* frags;
  CellB cell[3];
  const float* hfin_rd;       // dec: [3][2048][64] fp32
  float* hfin_wr;             // enc
  const float* lin_b;         // [1]
  float* y;                   // [2048][512]
};
struct PrepArgs {
  const float* w[13];         // (wih,whh) x 6 cells, then lin_w
  int din[13];
  unsigned short* out;
};

union HU { _Float16 h; unsigned short u; };
__device__ __forceinline__ unsigned short f2h(float x) { HU c; c.h = (_Float16)x; return c.u; }
__device__ __forceinline__ float h2f(unsigned short s) { HU c; c.u = s; return (float)c.h; }
__device__ __forceinline__ void wg_barrier() {
  asm volatile("s_waitcnt lgkmcnt(0)" ::: "memory");
  __builtin_amdgcn_s_barrier();
}

// ---------------------------------------------------------------------------
// Prep: f16 B-fragments (hi = f16(v), lo = f16(v - float(hi))) for 6 cells x
// {wih,whh} (cm 0..11) and lin_w (cm 12, tile 0, col 0).
// frag_idx = (cm*12+tile)*4 + s2*2 + sp; short off = frag_idx*512 + lane*8 + e.
// element: col c = tile*16+(lane&15); k = s2*32+(lane>>4)*8+e.
// ---------------------------------------------------------------------------
__global__ void prep_frags(PrepArgs P) {
  int id = blockIdx.x * 256 + threadIdx.x;       // 1248*256 = 319488
  int e    = id & 7;
  int lane = (id >> 3) & 63;
  int sp   = (id >> 9) & 1;
  int s2   = (id >> 10) & 1;
  int rest = id >> 11;
  int tile = rest % 12;
  int cm   = rest / 12;
  if (cm > 12) return;
  const float* W = P.w[cm];
  int din = P.din[cm];
  int c = tile * 16 + (lane & 15);
  int k = s2 * 32 + (lane >> 4) * 8 + e;
  float v = 0.f;
  if (cm == 12) {
    if (c == 0 && k < 60) v = W[k];              // lin_w row
  } else {
    int j = c & 63, sec = c >> 6;
    if (j < 60 && k < din) v = W[(sec * 60 + j) * din + k];
  }
  unsigned short hi = f2h(v);
  unsigned short o = sp ? f2h(v - h2f(hi)) : hi;
  P.out[id] = o;
}

// h-path: A x (Whi + Wlo), two independent 2-deep chains (4 MFMA)
__device__ __forceinline__ f32x4 mmh(f32x4 acc, const f16x8 A0, const f16x8 A1,
                                     const f16x8 B[2][2]) {
  f32x4 a2 = {0.f, 0.f, 0.f, 0.f};
  acc = __builtin_amdgcn_mfma_f32_16x16x32_f16(A0, B[0][0], acc, 0, 0, 0);
  a2  = __builtin_amdgcn_mfma_f32_16x16x32_f16(A0, B[0][1], a2,  0, 0, 0);
  acc = __builtin_amdgcn_mfma_f32_16x16x32_f16(A1, B[1][0], acc, 0, 0, 0);
  a2  = __builtin_amdgcn_mfma_f32_16x16x32_f16(A1, B[1][1], a2,  0, 0, 0);
  return acc + a2;
}
// x-path: A x Whi only (2 MFMA, one chain)
__device__ __forceinline__ f32x4 mmx(f32x4 acc, const f16x8 A0, const f16x8 A1,
                                     const f16x8 B[2]) {
  acc = __builtin_amdgcn_mfma_f32_16x16x32_f16(A0, B[0], acc, 0, 0, 0);
  acc = __builtin_amdgcn_mfma_f32_16x16x32_f16(A1, B[1], acc, 0, 0, 0);
  return acc;
}

// ---------------------------------------------------------------------------
// Fused 3-stage GRU pipeline, 2 sub-problems per block.
// Ring: [sub 0..1][region 0..5][row 0..15][col of RSTR] f16; region = g*2+par.
// ---------------------------------------------------------------------------
template <int IS_DEC>
__global__ __launch_bounds__(768, 3) void gru_phase(PhaseArgs P) {
  __shared__ alignas(16) unsigned short ring[2 * SUBSZ];

  const int tid  = threadIdx.x;
  const int lane = tid & 63;
  const int wid  = tid >> 6;
  const int g    = wid >> 2;      // layer/cell 0..2
  const int w    = wid & 3;       // col-tile 0..3
  const int c16  = lane & 15;
  const int q16  = lane >> 4;
  const int row_base = blockIdx.x * 32;
  const int c    = w * 16 + c16;  // logical h-col 0..63
  const bool cv  = (c < 60);
  const int cell = (IS_DEC ? 3 : 0) + g;
  const bool din1 = (g == 0);
  const int  ysub  = w;           // y-duty wave's sub index
  const bool yduty = (IS_DEC && g == 0 && w < 2);

  // per-lane LDS offsets (shorts)
  int wo[4];
#pragma unroll
  for (int q = 0; q < 4; ++q) wo[q] = (4 * q16 + q) * RSTR + c;
  const int ro0 = c16 * RSTR + q16 * 8;
  const int ro1 = ro0 + 32;

  // per-lane constants
  const float* bih = P.cell[g].bih;
  const float* bhh = P.cell[g].bhh;
  float b_r  = cv ? bih[c] + bhh[c]           : 0.f;
  float b_z  = cv ? bih[60 + c] + bhh[60 + c] : 0.f;
  float b_hn = cv ? bhh[120 + c]              : 0.f;
  float b_in = cv ? bih[120 + c]              : 0.f;
  float w_r = 0.f, w_z = 0.f, w_n = 0.f;
  if (din1 && cv) {
    const float* wv = P.cell[g].wih_vec;
    w_r = wv[c]; w_z = wv[60 + c]; w_n = wv[120 + c];
  }

  // persistent weight fragments: Bh hi/lo, Bx hi, Lw hi (shared by both subs)
  f16x8 Bh[3][2][2], Bx[3][2];
#pragma unroll
  for (int T = 0; T < 3; ++T)
#pragma unroll
    for (int s2 = 0; s2 < 2; ++s2) {
      const int tile = w + 4 * T;
#pragma unroll
      for (int sp = 0; sp < 2; ++sp)
        Bh[T][s2][sp] = *(const f16x8*)(P.frags +
            (size_t)(((cell * 2 + 1) * 12 + tile) * 4 + s2 * 2 + sp) * 512 + lane * 8);
      Bx[T][s2] = *(const f16x8*)(P.frags +
          (size_t)(((cell * 2 + 0) * 12 + tile) * 4 + s2 * 2 + 0) * 512 + lane * 8);
    }
  f16x8 Lw[2];
  float lb = 0.f;
  if (IS_DEC) {
    lb = P.lin_b[0];
#pragma unroll
    for (int s2 = 0; s2 < 2; ++s2)
      Lw[s2] = *(const f16x8*)(P.frags +
          (size_t)((12 * 12 + 0) * 4 + s2 * 2 + 0) * 512 + lane * 8);
  }

  // h0 per sub (enc: zeros; dec: encoder final h) into parity-1 region
  float hreg[2][4];
#pragma unroll
  for (int sb = 0; sb < 2; ++sb)
#pragma unroll
    for (int q = 0; q < 4; ++q) {
      float h0 = 0.f;
      if (IS_DEC && cv)
        h0 = P.hfin_rd[((size_t)(2 - g) * 2048 + row_base + sb * 16 + 4 * q16 + q) * 64 + c];
      hreg[sb][q] = h0;
      ring[sb * SUBSZ + (g * 2 + 1) * REG + wo[q]] = f2h(h0);
    }

  // x prefetch (t=0) for g0, both subs
  float xcur[2][4] = {};
  if (din1) {
#pragma unroll
    for (int sb = 0; sb < 2; ++sb)
#pragma unroll
      for (int q = 0; q < 4; ++q)
        xcur[sb][q] = P.xseq[(size_t)(row_base + sb * 16 + 4 * q16 + q) * 512];
  }
  wg_barrier();

#pragma unroll 1
  for (int s = 0; s < 514; ++s) {
    // decoder y_{s-3} = h2_{s-3} @ lin_w + lin_b (g0w0: sub0, g0w1: sub1)
    if (yduty && s >= 3) {
      const int yb = ysub * SUBSZ + (4 + ((s + 1) & 1)) * REG;
      f16x8 Y0 = *(const f16x8*)(ring + yb + ro0);
      f16x8 Y1 = *(const f16x8*)(ring + yb + ro1);
      f32x4 ya = {lb, lb, lb, lb};
      ya = mmx(ya, Y0, Y1, Lw);
      if (c16 == 0) {
#pragma unroll
        for (int q = 0; q < 4; ++q)
          P.y[(size_t)(row_base + ysub * 16 + 4 * q16 + q) * 512 + (s - 3)] = ya[q];
      }
    }

    const int t = s - g;
    if (t >= 0 && t < 512) {
      const int oR = (g * 2 + ((t + 1) & 1)) * REG;
      const int oW = (g * 2 + (t & 1)) * REG;
      const int oX = din1 ? 0 : ((g - 1) * 2 + (t & 1)) * REG;

#pragma unroll
      for (int sb = 0; sb < 2; ++sb) {
        // ---- A loads (f16 plane)
        f16x8 A0 = *(const f16x8*)(ring + sb * SUBSZ + oR + ro0);
        f16x8 A1 = *(const f16x8*)(ring + sb * SUBSZ + oR + ro1);
        f16x8 X0, X1;
        if (!din1) {
          X0 = *(const f16x8*)(ring + sb * SUBSZ + oX + ro0);
          X1 = *(const f16x8*)(ring + sb * SUBSZ + oX + ro1);
        }

        f32x4 aR  = {b_r, b_r, b_r, b_r};
        f32x4 aZ  = {b_z, b_z, b_z, b_z};
        f32x4 aHN = {b_hn, b_hn, b_hn, b_hn};
        f32x4 aIN = {b_in, b_in, b_in, b_in};
        aR  = mmh(aR,  A0, A1, Bh[0]);
        aZ  = mmh(aZ,  A0, A1, Bh[1]);
        aHN = mmh(aHN, A0, A1, Bh[2]);

        if (din1) {
#pragma unroll
          for (int q = 0; q < 4; ++q) {
            aR[q]  += xcur[sb][q] * w_r;
            aZ[q]  += xcur[sb][q] * w_z;
            aIN[q] += xcur[sb][q] * w_n;
          }
          if (t + 1 < 512) {                   // prefetch next step's x
            const float* xp = P.xseq + (size_t)(row_base + sb * 16) * 512 + (t + 1);
#pragma unroll
            for (int q = 0; q < 4; ++q) xcur[sb][q] = xp[(size_t)(4 * q16 + q) * 512];
          }
        } else {
          aR  = mmx(aR,  X0, X1, Bx[0]);
          aZ  = mmx(aZ,  X0, X1, Bx[1]);
          aIN = mmx(aIN, X0, X1, Bx[2]);
        }

        // ---- activations + state update (fp32), publish to parity t&1
        unsigned short* wp = ring + sb * SUBSZ + oW;
#pragma unroll
        for (int q = 0; q < 4; ++q) {
          float r = __builtin_amdgcn_rcpf(1.f + __expf(-aR[q]));
          float z = __builtin_amdgcn_rcpf(1.f + __expf(-aZ[q]));
          float na = aIN[q] + r * aHN[q];
          float e2 = __expf(2.f * na);
          float n  = __builtin_fmaf(-2.f, __builtin_amdgcn_rcpf(e2 + 1.f), 1.f);
          float h  = n + z * (hreg[sb][q] - n);
          hreg[sb][q] = h;
          wp[wo[q]] = f2h(h);
        }

        // ---- encoder: store final hidden state (fp32)
        if (!IS_DEC && t == 511) {
#pragma unroll
          for (int q = 0; q < 4; ++q)
            P.hfin_wr[((size_t)g * 2048 + row_base + sb * 16 + 4 * q16 + q) * 64 + c] =
                hreg[sb][q];
        }
      }
    }
    wg_barrier();
  }

  // decoder epilogue: y_511 (h2_511 in region 5 of own sub)
  if (yduty) {
    const int yb = ysub * SUBSZ + 5 * REG;
    f16x8 Y0 = *(const f16x8*)(ring + yb + ro0);
    f16x8 Y1 = *(const f16x8*)(ring + yb + ro1);
    f32x4 ya = {lb, lb, lb, lb};
    ya = mmx(ya, Y0, Y1, Lw);
    if (c16 == 0) {
#pragma unroll
      for (int q = 0; q < 4; ++q)
        P.y[(size_t)(row_base + ysub * 16 + 4 * q16 + q) * 512 + 511] = ya[q];
    }
  }
}

// ---------------------------------------------------------------------------
extern "C" void kernel_launch(void* const* d_in, const int* in_sizes, int n_in,
                              void* d_out, int out_size, void* d_ws, size_t ws_size,
                              hipStream_t stream) {
  (void)in_sizes; (void)n_in; (void)out_size; (void)ws_size;
  const float* inputs  = (const float*)d_in[0];
  const float* outputs = (const float*)d_in[1];

  unsigned short* frags = (unsigned short*)d_ws;            // 638976 B
  float* hfin = (float*)((char*)d_ws + 655360);             // 1.5 MB

  static const int ofs[6]  = {2, 6, 10, 14, 18, 22};  // enc0,enc1,enc2,c1,c2,c3
  static const int dins[6] = {1, 60, 60, 1, 60, 60};

  PrepArgs pa;
  for (int ci = 0; ci < 6; ++ci) {
    pa.w[ci * 2 + 0]   = (const float*)d_in[ofs[ci] + 0];  // wih
    pa.w[ci * 2 + 1]   = (const float*)d_in[ofs[ci] + 1];  // whh
    pa.din[ci * 2 + 0] = dins[ci];
    pa.din[ci * 2 + 1] = 60;
  }
  pa.w[12]   = (const float*)d_in[26];                     // lin_w
  pa.din[12] = 60;
  pa.out = frags;
  prep_frags<<<dim3(1248), dim3(256), 0, stream>>>(pa);

  PhaseArgs ea;
  ea.xseq = inputs; ea.frags = frags;
  for (int gg = 0; gg < 3; ++gg) {
    ea.cell[gg].bih     = (const float*)d_in[ofs[gg] + 2];
    ea.cell[gg].bhh     = (const float*)d_in[ofs[gg] + 3];
    ea.cell[gg].wih_vec = (const float*)d_in[ofs[gg] + 0];
  }
  ea.hfin_rd = hfin; ea.hfin_wr = hfin;
  ea.lin_b = (const float*)d_in[27];
  ea.y = (float*)d_out;
  gru_phase<0><<<dim3(64), dim3(768), 0, stream>>>(ea);

  PhaseArgs da = ea;
  da.xseq = outputs;
  for (int gg = 0; gg < 3; ++gg) {
    da.cell[gg].bih     = (const float*)d_in[ofs[3 + gg] + 2];
    da.cell[gg].bhh     = (const float*)d_in[ofs[3 + gg] + 3];
    da.cell[gg].wih_vec = (const float*)d_in[ofs[3 + gg] + 0];
  }
  gru_phase<1><<<dim3(64), dim3(768), 0, stream>>>(da);
}